// Round 1
// baseline (48067.044 us; speedup 1.0000x reference)
//
#include <hip/hip_runtime.h>
#include <hip/hip_bf16.h>

typedef __attribute__((ext_vector_type(8))) short bf16x8;
typedef __attribute__((ext_vector_type(4))) float f32x4;
typedef __attribute__((ext_vector_type(16))) float f32x16;

#define S_LEN 2048
#define BATCH 64
#define IDIM 256
#define HDIM 512
#define KDIM 768
#define ODIM 512
#define LDK 776   // comb/weight LDS row stride (shorts), 768 + 8 pad
#define LDH 520   // consumer h LDS row stride (shorts)
#define NPROD 128
#define NCONS 64
#define NBLK (NPROD + NCONS)

#define OFF_WST 49664            // 32*LDK*2 (comb region size)
#define OFF_PRE 49664            // pre aliases weight-stage region after prologue
#define OFF_BIAS 99328           // 49664 + 49664
#define SMEM_BYTES 99456         // + 32*4 bias

__device__ __forceinline__ unsigned short f2b(float f) {
  __hip_bfloat16 h = __float2bfloat16(f);
  return __builtin_bit_cast(unsigned short, h);
}
__device__ __forceinline__ float sigmoidf_(float x) { return 1.0f / (1.0f + __expf(-x)); }
__device__ __forceinline__ float tanhf_(float x) { return 1.0f - 2.0f / (1.0f + __expf(2.0f * x)); }

__global__ void lstm_init(const float* __restrict__ wh2o,
                          __hip_bfloat16* __restrict__ wh2o_bf,
                          __hip_bfloat16* __restrict__ h_all,
                          int* __restrict__ flags) {
  int idx = blockIdx.x * 256 + threadIdx.x;
  if (idx < ODIM * HDIM) wh2o_bf[idx] = __float2bfloat16(wh2o[idx]);
  if (idx < BATCH * HDIM) h_all[idx] = __float2bfloat16(0.0f);  // slot 0 = h0 = 0
  if (idx <= S_LEN) flags[idx] = 0;
}

__global__ __launch_bounds__(256) void lstm_persist(
    const float* __restrict__ x,
    const float* __restrict__ Wi, const float* __restrict__ bi,
    const float* __restrict__ Wf, const float* __restrict__ bfp,
    const float* __restrict__ Wg, const float* __restrict__ bgp,
    const float* __restrict__ Wo, const float* __restrict__ bop,
    const __hip_bfloat16* __restrict__ wh2o_bf, const float* __restrict__ bh2o,
    __hip_bfloat16* __restrict__ h_all, int* __restrict__ flags,
    float* __restrict__ out) {
  extern __shared__ char smem[];
  const int tid = threadIdx.x;
  const int lane = tid & 63;
  const int wave = tid >> 6;

  if (blockIdx.x < NPROD) {
    // ================= producer =================
    const int p = blockIdx.x;
    const int hg = p >> 1;   // h-group: 8 h-indices each
    const int bgr = p & 1;   // batch half: 32 rows each
    short* comb = (short*)smem;              // [32][LDK] bf16: k<256 x, k>=256 h
    short* wst = (short*)(smem + OFF_WST);   // [32][LDK] bf16 (prologue only)
    float* pre = (float*)(smem + OFF_PRE);   // [4][32][33] partial preacts
    float* blds = (float*)(smem + OFF_BIAS); // [32]

    // --- prologue: stage this wg's weight slab fp32->bf16 into LDS ---
    for (int i = tid; i < 32 * 192; i += 256) {
      int c = i / 192, k4 = i - c * 192;
      int gate = c >> 3;
      int hr = hg * 8 + (c & 7);
      const float* wsrc = (gate == 0) ? Wi : (gate == 1) ? Wf : (gate == 2) ? Wg : Wo;
      float4 v = *((const float4*)(wsrc + (size_t)hr * KDIM) + k4);
      ushort4 u;
      u.x = f2b(v.x); u.y = f2b(v.y); u.z = f2b(v.z); u.w = f2b(v.w);
      *(ushort4*)&wst[c * LDK + k4 * 4] = u;
    }
    if (tid < 32) {
      int gate = tid >> 3;
      const float* bsrc = (gate == 0) ? bi : (gate == 1) ? bfp : (gate == 2) ? bgp : bop;
      blds[tid] = bsrc[hg * 8 + (tid & 7)];
    }
    __syncthreads();
    // --- B fragments -> registers (wave w owns K slice [w*192, w*192+192)) ---
    const int bcol = lane & 31;
    const int ksub = (lane >> 5) * 8;
    bf16x8 bfrag[12];
#pragma unroll
    for (int kk = 0; kk < 12; ++kk)
      bfrag[kk] = *(const bf16x8*)&wst[bcol * LDK + wave * 192 + kk * 16 + ksub];
    __syncthreads();  // wst now reusable as pre

    const int grow = tid >> 3;  // local batch row 0..31 (gate phase)
    const int ghl = tid & 7;    // local h index 0..7
    float cst = 0.0f;           // c state, fp32, lives in reg for whole scan

    auto stage_x = [&](int t) {
      const float4* xs = (const float4*)(x + ((size_t)t * BATCH + bgr * 32) * IDIM);
      for (int i = tid; i < 2048; i += 256) {
        int r = i >> 6, k4 = i & 63;
        float4 v = xs[r * 64 + k4];
        ushort4 u;
        u.x = f2b(v.x); u.y = f2b(v.y); u.z = f2b(v.z); u.w = f2b(v.w);
        *(ushort4*)&comb[r * LDK + k4 * 4] = u;
      }
    };
    auto stage_h = [&](int slot) {
      const bf16x8* hs =
          (const bf16x8*)(h_all + (size_t)slot * BATCH * HDIM + (size_t)bgr * 32 * HDIM);
      for (int i = tid; i < 2048; i += 256) {
        int r = i >> 6, k8 = i & 63;
        *(bf16x8*)&comb[r * LDK + IDIM + k8 * 8] = hs[r * 64 + k8];
      }
    };

    stage_x(0);
    stage_h(0);
    const short* arow = &comb[(lane & 31) * LDK];
    const int akoff = wave * 192 + ksub;

    for (int t = 0; t < S_LEN; ++t) {
      __syncthreads();
      // gate GEMM: [32 rows x 32 gatecols], K split 4 ways over waves
      f32x16 acc = {};
#pragma unroll
      for (int kk = 0; kk < 12; ++kk) {
        bf16x8 a = *(const bf16x8*)(arow + akoff + kk * 16);
        acc = __builtin_amdgcn_mfma_f32_32x32x16_bf16(a, bfrag[kk], acc, 0, 0, 0);
      }
#pragma unroll
      for (int r = 0; r < 16; ++r) {
        int row = (r & 3) + 8 * (r >> 2) + 4 * (lane >> 5);
        pre[(wave * 32 + row) * 33 + (lane & 31)] = acc[r];
      }
      __syncthreads();
      // gate nonlinearities + state update (1 (row,h) pair per thread)
      float pi = blds[ghl], pf = blds[8 + ghl], pg = blds[16 + ghl], po = blds[24 + ghl];
#pragma unroll
      for (int w = 0; w < 4; ++w) {
        const float* pw = &pre[(w * 32 + grow) * 33];
        pi += pw[ghl]; pf += pw[8 + ghl]; pg += pw[16 + ghl]; po += pw[24 + ghl];
      }
      float ig = sigmoidf_(pi), fg = sigmoidf_(pf), gv = tanhf_(pg), og = sigmoidf_(po);
      cst = fg * cst + ig * gv;
      float hv = og * tanhf_(cst);
      h_all[(size_t)(t + 1) * BATCH * HDIM + (size_t)(bgr * 32 + grow) * HDIM + hg * 8 + ghl] =
          __float2bfloat16(hv);
      __threadfence();  // agent-scope release of h stores
      __syncthreads();
      if (tid == 0)
        __hip_atomic_fetch_add(&flags[t + 1], 1, __ATOMIC_RELEASE, __HIP_MEMORY_SCOPE_AGENT);
      if (t + 1 < S_LEN) {
        stage_x(t + 1);  // x-part: no dependency, prefetch before spin
        while (__hip_atomic_load(&flags[t + 1], __ATOMIC_RELAXED, __HIP_MEMORY_SCOPE_AGENT) <
               NPROD)
          __builtin_amdgcn_s_sleep(1);
        (void)__hip_atomic_load(&flags[t + 1], __ATOMIC_ACQUIRE, __HIP_MEMORY_SCOPE_AGENT);
        stage_h(t + 1);
      }
    }
  } else {
    // ================= consumer =================
    const int q = blockIdx.x - NPROD;
    short* hlds = (short*)smem;  // [64][LDH]
    for (int t = q; t < S_LEN; t += NCONS) {
      while (__hip_atomic_load(&flags[t + 1], __ATOMIC_RELAXED, __HIP_MEMORY_SCOPE_AGENT) < NPROD)
        __builtin_amdgcn_s_sleep(8);
      (void)__hip_atomic_load(&flags[t + 1], __ATOMIC_ACQUIRE, __HIP_MEMORY_SCOPE_AGENT);
      const bf16x8* hs = (const bf16x8*)(h_all + (size_t)(t + 1) * BATCH * HDIM);
      for (int i = tid; i < 4096; i += 256) {
        int r = i >> 6, k8 = i & 63;
        *(bf16x8*)&hlds[r * LDH + k8 * 8] = hs[i];
      }
      __syncthreads();
      const int r0 = wave * 16;
      const short* abase = &hlds[(r0 + (lane & 15)) * LDH + (lane >> 4) * 8];
      const short* bbase = (const short*)wh2o_bf + (size_t)(lane & 15) * HDIM + (lane >> 4) * 8;
      f32x4 acc[32];
      f32x4 zero = {0.f, 0.f, 0.f, 0.f};
#pragma unroll
      for (int n = 0; n < 32; ++n) acc[n] = zero;
      for (int kk = 0; kk < 16; ++kk) {
        bf16x8 a = *(const bf16x8*)(abase + kk * 32);
#pragma unroll
        for (int n = 0; n < 32; ++n) {
          bf16x8 b = *(const bf16x8*)(bbase + (size_t)n * 16 * HDIM + kk * 32);
          acc[n] = __builtin_amdgcn_mfma_f32_16x16x32_bf16(a, b, acc[n], 0, 0, 0);
        }
      }
      __syncthreads();  // hlds reads done before next iteration's staging
      // bias + log-softmax over 512 cols (spread over 16 lanes x 32 tiles)
      float mx[4] = {-3.0e38f, -3.0e38f, -3.0e38f, -3.0e38f};
#pragma unroll
      for (int n = 0; n < 32; ++n) {
        float bn = bh2o[n * 16 + (lane & 15)];
#pragma unroll
        for (int j = 0; j < 4; ++j) {
          acc[n][j] += bn;
          mx[j] = fmaxf(mx[j], acc[n][j]);
        }
      }
#pragma unroll
      for (int j = 0; j < 4; ++j) {
        mx[j] = fmaxf(mx[j], __shfl_xor(mx[j], 1));
        mx[j] = fmaxf(mx[j], __shfl_xor(mx[j], 2));
        mx[j] = fmaxf(mx[j], __shfl_xor(mx[j], 4));
        mx[j] = fmaxf(mx[j], __shfl_xor(mx[j], 8));
      }
      float sm[4] = {0.f, 0.f, 0.f, 0.f};
#pragma unroll
      for (int n = 0; n < 32; ++n) {
#pragma unroll
        for (int j = 0; j < 4; ++j) sm[j] += __expf(acc[n][j] - mx[j]);
      }
#pragma unroll
      for (int j = 0; j < 4; ++j) {
        sm[j] += __shfl_xor(sm[j], 1);
        sm[j] += __shfl_xor(sm[j], 2);
        sm[j] += __shfl_xor(sm[j], 4);
        sm[j] += __shfl_xor(sm[j], 8);
      }
      float ls[4];
#pragma unroll
      for (int j = 0; j < 4; ++j) ls[j] = mx[j] + __logf(sm[j]);
      float* ob = out + (size_t)t * BATCH * ODIM;
#pragma unroll
      for (int n = 0; n < 32; ++n) {
#pragma unroll
        for (int j = 0; j < 4; ++j) {
          int row = r0 + (lane >> 4) * 4 + j;
          ob[(size_t)row * ODIM + n * 16 + (lane & 15)] = acc[n][j] - ls[j];
        }
      }
    }
  }
}

extern "C" void kernel_launch(void* const* d_in, const int* in_sizes, int n_in,
                              void* d_out, int out_size, void* d_ws, size_t ws_size,
                              hipStream_t stream) {
  const float* x = (const float*)d_in[0];
  const float* Wi = (const float*)d_in[1];
  const float* bi = (const float*)d_in[2];
  const float* Wf = (const float*)d_in[3];
  const float* bf = (const float*)d_in[4];
  const float* Wg = (const float*)d_in[5];
  const float* bg = (const float*)d_in[6];
  const float* Wo = (const float*)d_in[7];
  const float* bo = (const float*)d_in[8];
  const float* Wh2o = (const float*)d_in[9];
  const float* bh2o = (const float*)d_in[10];

  char* ws = (char*)d_ws;
  int* flags = (int*)ws;
  __hip_bfloat16* h_all = (__hip_bfloat16*)(ws + 16384);
  size_t h_all_bytes = (size_t)(S_LEN + 1) * BATCH * HDIM * 2;
  __hip_bfloat16* wh2o_bf = (__hip_bfloat16*)(ws + 16384 + h_all_bytes);
  size_t needed = 16384 + h_all_bytes + (size_t)ODIM * HDIM * 2;
  if (ws_size < needed || n_in < 11) return;

  hipFuncSetAttribute((const void*)lstm_persist,
                      hipFuncAttributeMaxDynamicSharedMemorySize, SMEM_BYTES);

  lstm_init<<<1024, 256, 0, stream>>>(Wh2o, wh2o_bf, h_all, flags);
  lstm_persist<<<NBLK, 256, SMEM_BYTES, stream>>>(x, Wi, bi, Wf, bf, Wg, bg, Wo, bo,
                                                  wh2o_bf, bh2o, h_all, flags,
                                                  (float*)d_out);
}

// Round 2
// 18701.814 us; speedup vs baseline: 2.5702x; 2.5702x over previous
//
#include <hip/hip_runtime.h>
#include <hip/hip_bf16.h>

typedef __attribute__((ext_vector_type(8))) short bf16x8;
typedef __attribute__((ext_vector_type(4))) float f32x4;
typedef __attribute__((ext_vector_type(16))) float f32x16;
typedef unsigned long long u64;

#define S_LEN 2048
#define BATCH 64
#define IDIM 256
#define HDIM 512
#define KDIM 768
#define ODIM 512
#define LDK 776   // comb/weight LDS row stride (shorts), 768 + 8 pad
#define LDH 520   // consumer h LDS row stride (shorts)
#define NPROD 64
#define NCONS 64
#define NBLK (NPROD + NCONS)

// producer LDS map (bytes)
#define OFF_WST 49664    // comb = [32][LDK]*2B = 49664
#define OFF_PRE 49664    // pre aliases wst after prologue: [2][32][68] f32
#define OFF_BIAS 148992  // wst = [64][LDK]*2B = 99328 -> end 148992
#define OFF_HBUF 149248  // bias 64*4B
#define SMEM_BYTES 150272  // + hbuf 32*16*2B

__device__ __forceinline__ unsigned short f2b(float f) {
  __hip_bfloat16 h = __float2bfloat16(f);
  return __builtin_bit_cast(unsigned short, h);
}
__device__ __forceinline__ float sigmoidf_(float x) { return 1.0f / (1.0f + __expf(-x)); }
__device__ __forceinline__ float tanhf_(float x) { return 1.0f - 2.0f / (1.0f + __expf(2.0f * x)); }

// LLC-coherent (sc1) accesses: no L2 writeback/invalidate needed anywhere.
__device__ __forceinline__ u64 llc_load_u64(const u64* p) {
  return __hip_atomic_load(p, __ATOMIC_RELAXED, __HIP_MEMORY_SCOPE_AGENT);
}
__device__ __forceinline__ void llc_store_u64(u64* p, u64 v) {
  __hip_atomic_store(p, v, __ATOMIC_RELAXED, __HIP_MEMORY_SCOPE_AGENT);
}
__device__ __forceinline__ int llc_load_i32(const int* p) {
  return __hip_atomic_load(p, __ATOMIC_RELAXED, __HIP_MEMORY_SCOPE_AGENT);
}

__global__ void lstm_init(const float* __restrict__ wh2o,
                          __hip_bfloat16* __restrict__ wh2o_bf,
                          __hip_bfloat16* __restrict__ h_all,
                          int* __restrict__ flags) {
  int idx = blockIdx.x * 256 + threadIdx.x;
  if (idx < ODIM * HDIM) wh2o_bf[idx] = __float2bfloat16(wh2o[idx]);
  if (idx < BATCH * HDIM) h_all[idx] = __float2bfloat16(0.0f);  // slot 0 = h0 = 0
  if (idx <= S_LEN) flags[idx] = 0;
}

__global__ __launch_bounds__(256) void lstm_persist(
    const float* __restrict__ x,
    const float* __restrict__ Wi, const float* __restrict__ bi,
    const float* __restrict__ Wf, const float* __restrict__ bfp,
    const float* __restrict__ Wg, const float* __restrict__ bgp,
    const float* __restrict__ Wo, const float* __restrict__ bop,
    const __hip_bfloat16* __restrict__ wh2o_bf, const float* __restrict__ bh2o,
    __hip_bfloat16* __restrict__ h_all, int* __restrict__ flags,
    float* __restrict__ out) {
  extern __shared__ char smem[];
  const int tid = threadIdx.x;
  const int lane = tid & 63;
  const int wave = tid >> 6;

  if (blockIdx.x < NPROD) {
    // ================= producer: 16 h-cols x 32 batch rows each =================
    const int p = blockIdx.x;
    const int hg = p >> 1;  // h-group: 16 h-indices
    const int bgr = p & 1;  // batch half: 32 rows
    short* comb = (short*)smem;               // [32][LDK] bf16
    short* wst = (short*)(smem + OFF_WST);    // [64][LDK] bf16 (prologue only)
    float* pre = (float*)(smem + OFF_PRE);    // [2][32][68] partial preacts
    float* blds = (float*)(smem + OFF_BIAS);  // [64]
    short* hbuf = (short*)(smem + OFF_HBUF);  // [32][16]

    // --- prologue: stage weight slab (64 gate-cols x 768) fp32->bf16 ---
    for (int i = tid; i < 64 * 192; i += 256) {
      int c = i / 192, k4 = i - c * 192;
      int gate = c >> 4;
      int hr = hg * 16 + (c & 15);
      const float* wsrc = (gate == 0) ? Wi : (gate == 1) ? Wf : (gate == 2) ? Wg : Wo;
      float4 v = *((const float4*)(wsrc + (size_t)hr * KDIM) + k4);
      ushort4 u;
      u.x = f2b(v.x); u.y = f2b(v.y); u.z = f2b(v.z); u.w = f2b(v.w);
      *(ushort4*)&wst[c * LDK + k4 * 4] = u;
    }
    if (tid < 64) {
      int gate = tid >> 4;
      const float* bsrc = (gate == 0) ? bi : (gate == 1) ? bfp : (gate == 2) ? bgp : bop;
      blds[tid] = bsrc[hg * 16 + (tid & 15)];
    }
    __syncthreads();
    // --- B fragments -> registers. wave = (kh, c): col-tile c, K-half kh ---
    const int ct = wave & 1;
    const int kh = wave >> 1;
    const int bcol = ct * 32 + (lane & 31);
    const int ksub = (lane >> 5) * 8;
    bf16x8 bfrag[24];
#pragma unroll
    for (int kk = 0; kk < 24; ++kk)
      bfrag[kk] = *(const bf16x8*)&wst[bcol * LDK + kh * 384 + kk * 16 + ksub];
    __syncthreads();  // wst now reusable as pre

    float cst0 = 0.0f, cst1 = 0.0f;  // c state (2 (row,h) pairs per thread)

    auto stage_x = [&](int t) {
      const float4* xs = (const float4*)(x + ((size_t)t * BATCH + bgr * 32) * IDIM);
      for (int i = tid; i < 2048; i += 256) {
        int r = i >> 6, k4 = i & 63;
        float4 v = xs[r * 64 + k4];
        ushort4 u;
        u.x = f2b(v.x); u.y = f2b(v.y); u.z = f2b(v.z); u.w = f2b(v.w);
        *(ushort4*)&comb[r * LDK + k4 * 4] = u;
      }
    };
    auto stage_h = [&](int slot) {
      const u64* hs = (const u64*)h_all + ((size_t)slot * BATCH + bgr * 32) * (HDIM / 4);
      for (int i = tid; i < 4096; i += 256) {
        int r = i >> 7, cc = i & 127;
        u64 v = llc_load_u64(hs + r * 128 + cc);
        *(u64*)&comb[r * LDK + IDIM + cc * 4] = v;
      }
    };

    stage_x(0);
    stage_h(0);
    const short* arow = &comb[(lane & 31) * LDK];
    const int akoff = kh * 384 + ksub;

    for (int t = 0; t < S_LEN; ++t) {
      __syncthreads();
      // gate GEMM: [32 rows x 32 gatecols], K=384 per wave, 2 interleaved chains
      f32x16 acc0 = {}, acc1 = {};
#pragma unroll
      for (int kk = 0; kk < 24; kk += 2) {
        bf16x8 a0 = *(const bf16x8*)(arow + akoff + kk * 16);
        bf16x8 a1 = *(const bf16x8*)(arow + akoff + kk * 16 + 16);
        acc0 = __builtin_amdgcn_mfma_f32_32x32x16_bf16(a0, bfrag[kk], acc0, 0, 0, 0);
        acc1 = __builtin_amdgcn_mfma_f32_32x32x16_bf16(a1, bfrag[kk + 1], acc1, 0, 0, 0);
      }
#pragma unroll
      for (int r = 0; r < 16; ++r) {
        int row = (r & 3) + 8 * (r >> 2) + 4 * (lane >> 5);
        pre[(kh * 32 + row) * 68 + ct * 32 + (lane & 31)] = acc0[r] + acc1[r];
      }
      __syncthreads();
      // gate nonlinearities + state update: 2 (row,h) pairs per thread
#pragma unroll
      for (int pp = 0; pp < 2; ++pp) {
        int idx = tid * 2 + pp;
        int row = idx >> 4, hl = idx & 15;
        const float* p0 = &pre[row * 68];
        const float* p1 = &pre[(32 + row) * 68];
        float pi = blds[hl] + p0[hl] + p1[hl];
        float pf = blds[16 + hl] + p0[16 + hl] + p1[16 + hl];
        float pg = blds[32 + hl] + p0[32 + hl] + p1[32 + hl];
        float po = blds[48 + hl] + p0[48 + hl] + p1[48 + hl];
        float ig = sigmoidf_(pi), fg = sigmoidf_(pf), gv = tanhf_(pg), og = sigmoidf_(po);
        float& cst = pp ? cst1 : cst0;
        cst = fg * cst + ig * gv;
        float hv = og * tanhf_(cst);
        hbuf[row * 16 + hl] = (short)f2b(hv);
      }
      __syncthreads();
      // publish h (sc1 write-through to LLC), then drained flag bump
      if (tid < 128) {
        int r = tid >> 2, q4 = tid & 3;
        u64 v = *(const u64*)&hbuf[r * 16 + q4 * 4];
        u64* dst = (u64*)h_all + ((size_t)(t + 1) * BATCH + bgr * 32 + r) * (HDIM / 4) +
                   hg * 4 + q4;
        llc_store_u64(dst, v);
      }
      asm volatile("s_waitcnt vmcnt(0)" ::: "memory");  // h complete at LLC
      __syncthreads();
      if (tid == 0)
        __hip_atomic_fetch_add(&flags[t + 1], 1, __ATOMIC_RELAXED, __HIP_MEMORY_SCOPE_AGENT);
      if (t + 1 < S_LEN) {
        stage_x(t + 1);  // x: no dependency, overlap with wait
        if (wave == 0) {
          while (llc_load_i32(&flags[t + 1]) < NPROD) {}
        }
        __syncthreads();
        stage_h(t + 1);
      }
    }
  } else {
    // ================= consumer =================
    const int q = blockIdx.x - NPROD;
    short* hlds = (short*)smem;  // [64][LDH]
    for (int t = q; t < S_LEN; t += NCONS) {
      if (wave == 0) {
        while (llc_load_i32(&flags[t + 1]) < NPROD) __builtin_amdgcn_s_sleep(8);
      }
      __syncthreads();
      const u64* hs = (const u64*)h_all + (size_t)(t + 1) * BATCH * (HDIM / 4);
      for (int i = tid; i < 8192; i += 256) {
        int r = i >> 7, cc = i & 127;
        *(u64*)&hlds[r * LDH + cc * 4] = llc_load_u64(hs + i);
      }
      __syncthreads();
      const int r0 = wave * 16;
      const short* abase = &hlds[(r0 + (lane & 15)) * LDH + (lane >> 4) * 8];
      const short* bbase = (const short*)wh2o_bf + (size_t)(lane & 15) * HDIM + (lane >> 4) * 8;
      f32x4 acc[32];
      f32x4 zero = {0.f, 0.f, 0.f, 0.f};
#pragma unroll
      for (int n = 0; n < 32; ++n) acc[n] = zero;
      for (int kk = 0; kk < 16; ++kk) {
        bf16x8 a = *(const bf16x8*)(abase + kk * 32);
#pragma unroll
        for (int n = 0; n < 32; ++n) {
          bf16x8 b = *(const bf16x8*)(bbase + (size_t)n * 16 * HDIM + kk * 32);
          acc[n] = __builtin_amdgcn_mfma_f32_16x16x32_bf16(a, b, acc[n], 0, 0, 0);
        }
      }
      __syncthreads();  // hlds reads done before next iteration's staging
      // bias + log-softmax over 512 cols
      float mx[4] = {-3.0e38f, -3.0e38f, -3.0e38f, -3.0e38f};
#pragma unroll
      for (int n = 0; n < 32; ++n) {
        float bn = bh2o[n * 16 + (lane & 15)];
#pragma unroll
        for (int j = 0; j < 4; ++j) {
          acc[n][j] += bn;
          mx[j] = fmaxf(mx[j], acc[n][j]);
        }
      }
#pragma unroll
      for (int j = 0; j < 4; ++j) {
        mx[j] = fmaxf(mx[j], __shfl_xor(mx[j], 1));
        mx[j] = fmaxf(mx[j], __shfl_xor(mx[j], 2));
        mx[j] = fmaxf(mx[j], __shfl_xor(mx[j], 4));
        mx[j] = fmaxf(mx[j], __shfl_xor(mx[j], 8));
      }
      float sm[4] = {0.f, 0.f, 0.f, 0.f};
#pragma unroll
      for (int n = 0; n < 32; ++n) {
#pragma unroll
        for (int j = 0; j < 4; ++j) sm[j] += __expf(acc[n][j] - mx[j]);
      }
#pragma unroll
      for (int j = 0; j < 4; ++j) {
        sm[j] += __shfl_xor(sm[j], 1);
        sm[j] += __shfl_xor(sm[j], 2);
        sm[j] += __shfl_xor(sm[j], 4);
        sm[j] += __shfl_xor(sm[j], 8);
      }
      float ls[4];
#pragma unroll
      for (int j = 0; j < 4; ++j) ls[j] = mx[j] + __logf(sm[j]);
      float* ob = out + (size_t)t * BATCH * ODIM;
#pragma unroll
      for (int n = 0; n < 32; ++n) {
#pragma unroll
        for (int j = 0; j < 4; ++j) {
          int row = r0 + (lane >> 4) * 4 + j;
          ob[(size_t)row * ODIM + n * 16 + (lane & 15)] = acc[n][j] - ls[j];
        }
      }
    }
  }
}

extern "C" void kernel_launch(void* const* d_in, const int* in_sizes, int n_in,
                              void* d_out, int out_size, void* d_ws, size_t ws_size,
                              hipStream_t stream) {
  const float* x = (const float*)d_in[0];
  const float* Wi = (const float*)d_in[1];
  const float* bi = (const float*)d_in[2];
  const float* Wf = (const float*)d_in[3];
  const float* bf = (const float*)d_in[4];
  const float* Wg = (const float*)d_in[5];
  const float* bg = (const float*)d_in[6];
  const float* Wo = (const float*)d_in[7];
  const float* bo = (const float*)d_in[8];
  const float* Wh2o = (const float*)d_in[9];
  const float* bh2o = (const float*)d_in[10];

  char* ws = (char*)d_ws;
  int* flags = (int*)ws;
  __hip_bfloat16* h_all = (__hip_bfloat16*)(ws + 16384);
  size_t h_all_bytes = (size_t)(S_LEN + 1) * BATCH * HDIM * 2;
  __hip_bfloat16* wh2o_bf = (__hip_bfloat16*)(ws + 16384 + h_all_bytes);
  size_t needed = 16384 + h_all_bytes + (size_t)ODIM * HDIM * 2;
  if (ws_size < needed || n_in < 11) return;

  hipFuncSetAttribute((const void*)lstm_persist,
                      hipFuncAttributeMaxDynamicSharedMemorySize, SMEM_BYTES);

  lstm_init<<<1024, 256, 0, stream>>>(Wh2o, wh2o_bf, h_all, flags);
  lstm_persist<<<NBLK, 256, SMEM_BYTES, stream>>>(x, Wi, bi, Wf, bf, Wg, bg, Wo, bo,
                                                  wh2o_bf, bh2o, h_all, flags,
                                                  (float*)d_out);
}